// Round 5
// baseline (2368.652 us; speedup 1.0000x reference)
//
#include <hip/hip_runtime.h>
#include <math.h>

#define TT  1024
#define DD  2048
#define NHH 2048
#define CC  1000

// ---------------------------------------------------------------------------
// k_init: poison all 4 exchange slots' tags every launch (tag 0xFFFFFFFF
// never matches a real epoch < 1024). Harness poisons d_ws too; this is belt
// and suspenders.
// ---------------------------------------------------------------------------
__global__ void k_init(unsigned long long* __restrict__ Hbuf) {
    int i = blockIdx.x * blockDim.x + threadIdx.x;
    if (i < 4 * NHH) Hbuf[i] = 0xFFFFFFFF00000000ull;
}

// ---------------------------------------------------------------------------
// GEMM: XH = x @ Wh^T ; XZ = x @ Wz^T + bz   (fp32, 64x64 tile, BK=32)
// ---------------------------------------------------------------------------
__global__ __launch_bounds__(256) void k_gemm(const float* __restrict__ X,
                                              const float* __restrict__ Wh,
                                              const float* __restrict__ Wz,
                                              const float* __restrict__ bz,
                                              float* __restrict__ XH,
                                              float* __restrict__ XZ) {
    __shared__ float As[32][68];   // [k][m]
    __shared__ float Bs[32][68];   // [k][n]
    const int z = blockIdx.z;
    const float* __restrict__ W = z ? Wz : Wh;
    float* __restrict__ OUT = z ? XZ : XH;
    const int n0 = blockIdx.x * 64;
    const int m0 = blockIdx.y * 64;
    const int tid = threadIdx.x;
    const int tx = tid & 15, ty = tid >> 4;
    const int lr = tid >> 2;           // 0..63 row within tile
    const int lc = (tid & 3) * 8;      // 0,8,16,24 col base

    float acc[4][4] = {};
    for (int k0 = 0; k0 < DD; k0 += 32) {
        float4 a0 = *(const float4*)&X[(size_t)(m0 + lr) * DD + k0 + lc];
        float4 a1 = *(const float4*)&X[(size_t)(m0 + lr) * DD + k0 + lc + 4];
        float4 b0 = *(const float4*)&W[(size_t)(n0 + lr) * DD + k0 + lc];
        float4 b1 = *(const float4*)&W[(size_t)(n0 + lr) * DD + k0 + lc + 4];
        As[lc+0][lr]=a0.x; As[lc+1][lr]=a0.y; As[lc+2][lr]=a0.z; As[lc+3][lr]=a0.w;
        As[lc+4][lr]=a1.x; As[lc+5][lr]=a1.y; As[lc+6][lr]=a1.z; As[lc+7][lr]=a1.w;
        Bs[lc+0][lr]=b0.x; Bs[lc+1][lr]=b0.y; Bs[lc+2][lr]=b0.z; Bs[lc+3][lr]=b0.w;
        Bs[lc+4][lr]=b1.x; Bs[lc+5][lr]=b1.y; Bs[lc+6][lr]=b1.z; Bs[lc+7][lr]=b1.w;
        __syncthreads();
#pragma unroll
        for (int kk = 0; kk < 32; ++kk) {
            float4 av = *(const float4*)&As[kk][ty * 4];
            float4 bv = *(const float4*)&Bs[kk][tx * 4];
            acc[0][0] = fmaf(av.x, bv.x, acc[0][0]); acc[0][1] = fmaf(av.x, bv.y, acc[0][1]);
            acc[0][2] = fmaf(av.x, bv.z, acc[0][2]); acc[0][3] = fmaf(av.x, bv.w, acc[0][3]);
            acc[1][0] = fmaf(av.y, bv.x, acc[1][0]); acc[1][1] = fmaf(av.y, bv.y, acc[1][1]);
            acc[1][2] = fmaf(av.y, bv.z, acc[1][2]); acc[1][3] = fmaf(av.y, bv.w, acc[1][3]);
            acc[2][0] = fmaf(av.z, bv.x, acc[2][0]); acc[2][1] = fmaf(av.z, bv.y, acc[2][1]);
            acc[2][2] = fmaf(av.z, bv.z, acc[2][2]); acc[2][3] = fmaf(av.z, bv.w, acc[2][3]);
            acc[3][0] = fmaf(av.w, bv.x, acc[3][0]); acc[3][1] = fmaf(av.w, bv.y, acc[3][1]);
            acc[3][2] = fmaf(av.w, bv.z, acc[3][2]); acc[3][3] = fmaf(av.w, bv.w, acc[3][3]);
        }
        __syncthreads();
    }
    float4 bias = make_float4(0.f, 0.f, 0.f, 0.f);
    if (z) bias = *(const float4*)&bz[n0 + tx * 4];
#pragma unroll
    for (int i = 0; i < 4; ++i) {
        float4 o = make_float4(acc[i][0] + bias.x, acc[i][1] + bias.y,
                               acc[i][2] + bias.z, acc[i][3] + bias.w);
        *(float4*)&OUT[(size_t)(m0 + ty * 4 + i) * NHH + n0 + tx * 4] = o;
    }
}

// ---------------------------------------------------------------------------
// Recurrent scan — R2/R4 synchronization skeleton (proven race-free across
// graph replays), but U lives in LDS (128 KB/CU), NOT registers. R2/R4
// evidence: compiler refuses to keep 128 f32/lane resident (VGPR_Count=100,
// scratch/global re-stream of 32 MB/step = the 1.7 µs/step plateau). LDS
// cannot be spilled: per-step U read = 128 KB/CU at 256 B/clk ≈ 640 cy,
// overlapped with 512 cy FMA across 4 waves.
// LDS: Us 128 KB + Hs 8 KB + dot_s = 139.3 KB < 160 KB.
// 4-slot tagged (epoch<<32|f32bits) Hbuf, relaxed agent-scope u64 atomics.
// ---------------------------------------------------------------------------
__global__ __launch_bounds__(256, 1) void k_recur(
    const float* __restrict__ XH, const float* __restrict__ XZ,
    const float* __restrict__ Uh, const float* __restrict__ Uz,
    const float* __restrict__ zt0, const float* __restrict__ ht0,
    const float* __restrict__ hp0,
    unsigned long long* __restrict__ Hbuf) {
    __shared__ float Us[16][NHH];   // rows 0..7 = Uz[base8+r], 8..15 = Uh[base8+r]
    __shared__ float Hs[NHH];
    __shared__ float dot_s[16];
    const int tid  = threadIdx.x;
    const int wave = tid >> 6, lane = tid & 63;
    const int base8 = blockIdx.x * 8;

    // stage this WG's 16 U rows into LDS (coalesced: 8 floats/thread/row)
#pragma unroll
    for (int r = 0; r < 8; ++r) {
        const float* __restrict__ gz = Uz + (size_t)(base8 + r) * NHH + tid * 8;
        const float* __restrict__ gh = Uh + (size_t)(base8 + r) * NHH + tid * 8;
        *(float4*)&Us[r][tid * 8]     = *(const float4*)&gz[0];
        *(float4*)&Us[r][tid * 8 + 4] = *(const float4*)&gz[4];
        *(float4*)&Us[8 + r][tid * 8]     = *(const float4*)&gh[0];
        *(float4*)&Us[8 + r][tid * 8 + 4] = *(const float4*)&gh[4];
    }

    // Hs = P_0 = hprev0
#pragma unroll
    for (int k = 0; k < 8; ++k) Hs[k * 256 + tid] = hp0[k * 256 + tid];

    // own P_1 from initial gates; publish epoch 1
    float p_cur = 0.f;
    if (tid < 8) {
        float z0 = zt0[base8 + tid], g0 = ht0[base8 + tid], p0 = hp0[base8 + tid];
        p_cur = (1.0f - z0) * p0 + z0 * g0;
        unsigned long long pr = (1ull << 32) | (unsigned long long)__float_as_uint(p_cur);
        __hip_atomic_store(&Hbuf[(size_t)1 * NHH + base8 + tid], pr,
                           __ATOMIC_RELAXED, __HIP_MEMORY_SCOPE_AGENT);
    }
    __syncthreads();

    // this wave's 4 LDS U rows: wave0: Us[0..3] wave1: Us[4..7]
    //                           wave2: Us[8..11] wave3: Us[12..15]
    const int lr0 = (wave >> 1) * 8 + (wave & 1) * 4;
    const float* __restrict__ U0 = Us[lr0 + 0];
    const float* __restrict__ U1 = Us[lr0 + 1];
    const float* __restrict__ U2 = Us[lr0 + 2];
    const float* __restrict__ U3 = Us[lr0 + 3];

    for (int t = 1; t < TT; ++t) {
        // (i) issue epoch-t loads; consumed after matvec+reduce
        const unsigned long long* __restrict__ src = Hbuf + (size_t)(t & 3) * NHH;
        unsigned long long pv[8];
#pragma unroll
        for (int k = 0; k < 8; ++k)
            pv[k] = __hip_atomic_load(&src[k * 256 + tid], __ATOMIC_RELAXED, __HIP_MEMORY_SCOPE_AGENT);
        float xzv = 0.f, xhv = 0.f;
        if (tid < 8) {
            xzv = XZ[(size_t)(t - 1) * NHH + base8 + tid];
            xhv = XH[(size_t)(t - 1) * NHH + base8 + tid];
        }
        // (ii) matvec: U @ P_{t-1}, U and H both from LDS (b128 reads)
        float a0 = 0.f, a1 = 0.f, a2 = 0.f, a3 = 0.f;
#pragma unroll
        for (int c = 0; c < 8; ++c) {
            const int o = c * 256 + lane * 4;
            float4 h4 = *(const float4*)&Hs[o];
            float4 u0 = *(const float4*)&U0[o];
            float4 u1 = *(const float4*)&U1[o];
            float4 u2 = *(const float4*)&U2[o];
            float4 u3 = *(const float4*)&U3[o];
            a0 = fmaf(u0.x, h4.x, fmaf(u0.y, h4.y, fmaf(u0.z, h4.z, fmaf(u0.w, h4.w, a0))));
            a1 = fmaf(u1.x, h4.x, fmaf(u1.y, h4.y, fmaf(u1.z, h4.z, fmaf(u1.w, h4.w, a1))));
            a2 = fmaf(u2.x, h4.x, fmaf(u2.y, h4.y, fmaf(u2.z, h4.z, fmaf(u2.w, h4.w, a2))));
            a3 = fmaf(u3.x, h4.x, fmaf(u3.y, h4.y, fmaf(u3.z, h4.z, fmaf(u3.w, h4.w, a3))));
        }
#pragma unroll
        for (int off = 32; off > 0; off >>= 1) {
            a0 += __shfl_xor(a0, off);
            a1 += __shfl_xor(a1, off);
            a2 += __shfl_xor(a2, off);
            a3 += __shfl_xor(a3, off);
        }
        if (lane == 0) {
            int di = ((wave & 1) * 4) + ((wave >> 1) * 8); // Uz -> 0..7, Uh -> 8..15
            dot_s[di + 0] = a0; dot_s[di + 1] = a1; dot_s[di + 2] = a2; dot_s[di + 3] = a3;
        }
        __syncthreads();
        // (iii) gates from P_{t-1} dots; P_{t+1} = (1-z)*P_t + z*g; publish
        if (tid < 8) {
            float z = 1.0f / (1.0f + expf(-(xzv + dot_s[tid])));
            float g = tanhf(xhv + dot_s[8 + tid]);
            float pn = (1.0f - z) * p_cur + z * g;
            p_cur = pn;
            unsigned long long pr = ((unsigned long long)(unsigned)(t + 1) << 32)
                                  | (unsigned long long)__float_as_uint(pn);
            __hip_atomic_store(&Hbuf[(size_t)((t + 1) & 3) * NHH + base8 + tid], pr,
                               __ATOMIC_RELAXED, __HIP_MEMORY_SCOPE_AGENT);
        }
        // (iv) validate epoch-t tags; batched parallel retry of stale ones
        for (;;) {
            unsigned stale = 0;
#pragma unroll
            for (int k = 0; k < 8; ++k)
                if ((unsigned)(pv[k] >> 32) != (unsigned)t) stale |= (1u << k);
            if (!stale) break;
#pragma unroll
            for (int k = 0; k < 8; ++k)
                if (stale & (1u << k))
                    pv[k] = __hip_atomic_load(&src[k * 256 + tid], __ATOMIC_RELAXED, __HIP_MEMORY_SCOPE_AGENT);
        }
        // (v) fill Hs = P_t; barrier
#pragma unroll
        for (int k = 0; k < 8; ++k) Hs[k * 256 + tid] = __uint_as_float((unsigned)pv[k]);
        __syncthreads();
    }
}

// ---------------------------------------------------------------------------
// logits[r] = Wout[r,:] . P_1024   (epoch 1024 -> slot 0, value in low bits)
// ---------------------------------------------------------------------------
__global__ __launch_bounds__(256) void k_logits(const unsigned long long* __restrict__ Hbuf,
                                                const float* __restrict__ Wout,
                                                float* __restrict__ lg) {
    __shared__ float Hs[NHH];
    const int tid = threadIdx.x;
    for (int k = tid; k < NHH; k += 256) Hs[k] = __uint_as_float((unsigned)Hbuf[k]);
    __syncthreads();
    const int wave = tid >> 6, lane = tid & 63;
    const int row = blockIdx.x * 4 + wave;
    float a = 0.f;
#pragma unroll
    for (int c = 0; c < 8; ++c) {
        float4 w = *(const float4*)&Wout[(size_t)row * NHH + c * 256 + lane * 4];
        float4 h = *(const float4*)&Hs[c * 256 + lane * 4];
        a = fmaf(w.x, h.x, fmaf(w.y, h.y, fmaf(w.z, h.z, fmaf(w.w, h.w, a))));
    }
#pragma unroll
    for (int off = 32; off > 0; off >>= 1) a += __shfl_xor(a, off);
    if (lane == 0) lg[row] = a;
}

// ---------------------------------------------------------------------------
// softmax over 1000 logits, single block
// ---------------------------------------------------------------------------
__global__ __launch_bounds__(1024) void k_softmax(const float* __restrict__ lg,
                                                  float* __restrict__ out) {
    const int i = threadIdx.x;
    __shared__ float red[16];
    __shared__ float bc[2];
    float v = (i < CC) ? lg[i] : -3.0e38f;
    float m = v;
#pragma unroll
    for (int off = 32; off > 0; off >>= 1) m = fmaxf(m, __shfl_xor(m, off));
    if ((i & 63) == 0) red[i >> 6] = m;
    __syncthreads();
    if (i == 0) { float mm = red[0]; for (int k = 1; k < 16; ++k) mm = fmaxf(mm, red[k]); bc[0] = mm; }
    __syncthreads();
    float e = (i < CC) ? expf(v - bc[0]) : 0.f;
    float s = e;
#pragma unroll
    for (int off = 32; off > 0; off >>= 1) s += __shfl_xor(s, off);
    if ((i & 63) == 0) red[i >> 6] = s;
    __syncthreads();
    if (i == 0) { float ss = 0.f; for (int k = 0; k < 16; ++k) ss += red[k]; bc[1] = ss; }
    __syncthreads();
    if (i < CC) out[i] = e / bc[1];
}

extern "C" void kernel_launch(void* const* d_in, const int* in_sizes, int n_in,
                              void* d_out, int out_size, void* d_ws, size_t ws_size,
                              hipStream_t stream) {
    const float* x    = (const float*)d_in[0];
    const float* Wh   = (const float*)d_in[1];
    const float* Wz   = (const float*)d_in[2];
    // d_in[3] = Wr  (dead code in reference)
    const float* Uh   = (const float*)d_in[4];
    const float* Uz   = (const float*)d_in[5];
    const float* bz   = (const float*)d_in[6];
    // d_in[7] = Ur, d_in[8] = br (dead code)
    const float* Wout = (const float*)d_in[9];
    // d_in[10] = h0 (overwritten before first use since T>=1)
    const float* zt0  = (const float*)d_in[11];
    const float* ht0  = (const float*)d_in[12];
    const float* hp0  = (const float*)d_in[13];
    float* out = (float*)d_out;

    float* XH = (float*)d_ws;                                   // T*NH f32
    float* XZ = XH + (size_t)TT * NHH;                          // T*NH f32
    unsigned long long* Hbuf = (unsigned long long*)(XZ + (size_t)TT * NHH); // 4*NH u64
    float* lg = (float*)(Hbuf + 4 * NHH);                       // CC f32

    k_init<<<dim3((4 * NHH + 255) / 256), dim3(256), 0, stream>>>(Hbuf);
    k_gemm<<<dim3(NHH / 64, TT / 64, 2), dim3(256), 0, stream>>>(x, Wh, Wz, bz, XH, XZ);
    k_recur<<<dim3(256), dim3(256), 0, stream>>>(XH, XZ, Uh, Uz, zt0, ht0, hp0, Hbuf);
    k_logits<<<dim3(250), dim3(256), 0, stream>>>(Hbuf, Wout, lg);
    k_softmax<<<dim3(1), dim3(1024), 0, stream>>>(lg, out);
}

// Round 6
// 2098.735 us; speedup vs baseline: 1.1286x; 1.1286x over previous
//
#include <hip/hip_runtime.h>
#include <math.h>

#define TT  1024
#define DD  2048
#define NHH 2048
#define CC  1000

#define LDS_LOAD_ACQ(P)  __hip_atomic_load((P), __ATOMIC_ACQUIRE, __HIP_MEMORY_SCOPE_WORKGROUP)
#define LDS_ADD_REL(P)   __hip_atomic_fetch_add((P), 1, __ATOMIC_RELEASE, __HIP_MEMORY_SCOPE_WORKGROUP)

// ---------------------------------------------------------------------------
// k_init: poison all 4 exchange slots' tags EVERY launch. CRITICAL for graph
// replays: leftover tags 1021..1024 from the previous replay exactly match
// expected tags at t=1021..1023 of the next run (this was R3's divergence).
// ---------------------------------------------------------------------------
__global__ void k_init(unsigned long long* __restrict__ Hbuf) {
    int i = blockIdx.x * blockDim.x + threadIdx.x;
    if (i < 4 * NHH) Hbuf[i] = 0xFFFFFFFF00000000ull;
}

// ---------------------------------------------------------------------------
// GEMM: XH = x @ Wh^T ; XZ = x @ Wz^T + bz   (fp32, 64x64 tile, BK=32)
// ---------------------------------------------------------------------------
__global__ __launch_bounds__(256) void k_gemm(const float* __restrict__ X,
                                              const float* __restrict__ Wh,
                                              const float* __restrict__ Wz,
                                              const float* __restrict__ bz,
                                              float* __restrict__ XH,
                                              float* __restrict__ XZ) {
    __shared__ float As[32][68];   // [k][m]
    __shared__ float Bs[32][68];   // [k][n]
    const int z = blockIdx.z;
    const float* __restrict__ W = z ? Wz : Wh;
    float* __restrict__ OUT = z ? XZ : XH;
    const int n0 = blockIdx.x * 64;
    const int m0 = blockIdx.y * 64;
    const int tid = threadIdx.x;
    const int tx = tid & 15, ty = tid >> 4;
    const int lr = tid >> 2;           // 0..63 row within tile
    const int lc = (tid & 3) * 8;      // 0,8,16,24 col base

    float acc[4][4] = {};
    for (int k0 = 0; k0 < DD; k0 += 32) {
        float4 a0 = *(const float4*)&X[(size_t)(m0 + lr) * DD + k0 + lc];
        float4 a1 = *(const float4*)&X[(size_t)(m0 + lr) * DD + k0 + lc + 4];
        float4 b0 = *(const float4*)&W[(size_t)(n0 + lr) * DD + k0 + lc];
        float4 b1 = *(const float4*)&W[(size_t)(n0 + lr) * DD + k0 + lc + 4];
        As[lc+0][lr]=a0.x; As[lc+1][lr]=a0.y; As[lc+2][lr]=a0.z; As[lc+3][lr]=a0.w;
        As[lc+4][lr]=a1.x; As[lc+5][lr]=a1.y; As[lc+6][lr]=a1.z; As[lc+7][lr]=a1.w;
        Bs[lc+0][lr]=b0.x; Bs[lc+1][lr]=b0.y; Bs[lc+2][lr]=b0.z; Bs[lc+3][lr]=b0.w;
        Bs[lc+4][lr]=b1.x; Bs[lc+5][lr]=b1.y; Bs[lc+6][lr]=b1.z; Bs[lc+7][lr]=b1.w;
        __syncthreads();
#pragma unroll
        for (int kk = 0; kk < 32; ++kk) {
            float4 av = *(const float4*)&As[kk][ty * 4];
            float4 bv = *(const float4*)&Bs[kk][tx * 4];
            acc[0][0] = fmaf(av.x, bv.x, acc[0][0]); acc[0][1] = fmaf(av.x, bv.y, acc[0][1]);
            acc[0][2] = fmaf(av.x, bv.z, acc[0][2]); acc[0][3] = fmaf(av.x, bv.w, acc[0][3]);
            acc[1][0] = fmaf(av.y, bv.x, acc[1][0]); acc[1][1] = fmaf(av.y, bv.y, acc[1][1]);
            acc[1][2] = fmaf(av.y, bv.z, acc[1][2]); acc[1][3] = fmaf(av.y, bv.w, acc[1][3]);
            acc[2][0] = fmaf(av.z, bv.x, acc[2][0]); acc[2][1] = fmaf(av.z, bv.y, acc[2][1]);
            acc[2][2] = fmaf(av.z, bv.z, acc[2][2]); acc[2][3] = fmaf(av.z, bv.w, acc[2][3]);
            acc[3][0] = fmaf(av.w, bv.x, acc[3][0]); acc[3][1] = fmaf(av.w, bv.y, acc[3][1]);
            acc[3][2] = fmaf(av.w, bv.z, acc[3][2]); acc[3][3] = fmaf(av.w, bv.w, acc[3][3]);
        }
        __syncthreads();
    }
    float4 bias = make_float4(0.f, 0.f, 0.f, 0.f);
    if (z) bias = *(const float4*)&bz[n0 + tx * 4];
#pragma unroll
    for (int i = 0; i < 4; ++i) {
        float4 o = make_float4(acc[i][0] + bias.x, acc[i][1] + bias.y,
                               acc[i][2] + bias.z, acc[i][3] + bias.w);
        *(float4*)&OUT[(size_t)(m0 + ty * 4 + i) * NHH + n0 + tx * 4] = o;
    }
}

// ---------------------------------------------------------------------------
// Recurrent scan v4: producer/consumer wave specialization.
// 256 WGs x 512 threads. Waves 0-3 COMPUTE: matvec (U in LDS, R5-proven
// layout), butterfly reduce, gates (tid<8), publish. Waves 4-7 COMM: poll
// Hbuf tags, validate, fill Hs. The L3 publish->visibility RTT overlaps the
// matvec instead of following it (R1-R5 evidence: serialized skeleton
// plateaus at 1.7-2.0 us/step with only ~1000cy of work).
// Sync: NO per-step barrier. Two monotone LDS counters:
//   mv_cnt   += 4/step (one per compute wave, release, after matvec reads +
//              dot_s write). Guards Hs overwrite + dot_s consumption.
//   fill_cnt += 4/step (one per comm wave, release, after Hs writes).
//              Guards matvec start.
// Hs double-buffered (parity t); dot_s double-buffered (parity t) - WAR on
// dot_s[t&1] at t+2 requires fill t+1 <- local publish t+1 <- gates t done.
// Hbuf: 4-slot tagged (epoch<<32|f32bits), relaxed agent-scope u64 atomics,
// poisoned every launch by k_init.
// ---------------------------------------------------------------------------
__global__ __launch_bounds__(512, 2) void k_recur(
    const float* __restrict__ XH, const float* __restrict__ XZ,
    const float* __restrict__ Uh, const float* __restrict__ Uz,
    const float* __restrict__ zt0, const float* __restrict__ ht0,
    const float* __restrict__ hp0,
    unsigned long long* __restrict__ Hbuf) {
    __shared__ float Us[16][NHH];     // 128 KB: rows 0..7 Uz, 8..15 Uh
    __shared__ float Hs[2][NHH];      // 16 KB, parity by t
    __shared__ float dot_s[2][16];    // parity by t
    __shared__ int mv_cnt, fill_cnt;
    const int tid  = threadIdx.x;
    const int wave = tid >> 6, lane = tid & 63;
    const int base8 = blockIdx.x * 8;

    if (tid == 0) { mv_cnt = 0; fill_cnt = 0; }

    // stage U rows into LDS: each thread one float4 per row (coalesced)
    {
        const int c4 = tid * 4;
#pragma unroll
        for (int r = 0; r < 8; ++r) {
            *(float4*)&Us[r][c4]     = *(const float4*)&Uz[(size_t)(base8 + r) * NHH + c4];
            *(float4*)&Us[8 + r][c4] = *(const float4*)&Uh[(size_t)(base8 + r) * NHH + c4];
        }
    }
    // Hs[0] = P_0 = hprev0
    *(float4*)&Hs[0][tid * 4] = *(const float4*)&hp0[tid * 4];

    // own P_1 from initial gates; publish epoch 1; preload x-proj row 0
    float p_cur = 0.f, xz_cur = 0.f, xh_cur = 0.f;
    if (tid < 8) {
        float z0 = zt0[base8 + tid], g0 = ht0[base8 + tid], p0 = hp0[base8 + tid];
        p_cur = (1.0f - z0) * p0 + z0 * g0;
        unsigned long long pr = (1ull << 32) | (unsigned long long)__float_as_uint(p_cur);
        __hip_atomic_store(&Hbuf[(size_t)1 * NHH + base8 + tid], pr,
                           __ATOMIC_RELAXED, __HIP_MEMORY_SCOPE_AGENT);
        xz_cur = XZ[base8 + tid];
        xh_cur = XH[base8 + tid];
    }
    __syncthreads();   // the ONLY barrier

    if (wave < 4) {
        // ----------------- COMPUTE role (waves 0-3) -----------------
        const int lr0 = (wave >> 1) * 8 + (wave & 1) * 4;
        const float* __restrict__ U0 = Us[lr0 + 0];
        const float* __restrict__ U1 = Us[lr0 + 1];
        const float* __restrict__ U2 = Us[lr0 + 2];
        const float* __restrict__ U3 = Us[lr0 + 3];
        const int di = ((wave & 1) * 4) + ((wave >> 1) * 8);  // Uz->0..7, Uh->8..15

        for (int t = 1; t < TT; ++t) {
            // wait for P_{t-1} in Hs[(t-1)&1]  (t=1: prologue-filled)
            if (t > 1)
                while (LDS_LOAD_ACQ(&fill_cnt) < 4 * (t - 1)) __builtin_amdgcn_s_sleep(0);
            const float* __restrict__ HA = Hs[(t - 1) & 1];
            float a0 = 0.f, a1 = 0.f, a2 = 0.f, a3 = 0.f;
#pragma unroll
            for (int c = 0; c < 8; ++c) {
                const int o = c * 256 + lane * 4;
                float4 h4 = *(const float4*)&HA[o];
                float4 u0 = *(const float4*)&U0[o];
                float4 u1 = *(const float4*)&U1[o];
                float4 u2 = *(const float4*)&U2[o];
                float4 u3 = *(const float4*)&U3[o];
                a0 = fmaf(u0.x, h4.x, fmaf(u0.y, h4.y, fmaf(u0.z, h4.z, fmaf(u0.w, h4.w, a0))));
                a1 = fmaf(u1.x, h4.x, fmaf(u1.y, h4.y, fmaf(u1.z, h4.z, fmaf(u1.w, h4.w, a1))));
                a2 = fmaf(u2.x, h4.x, fmaf(u2.y, h4.y, fmaf(u2.z, h4.z, fmaf(u2.w, h4.w, a2))));
                a3 = fmaf(u3.x, h4.x, fmaf(u3.y, h4.y, fmaf(u3.z, h4.z, fmaf(u3.w, h4.w, a3))));
            }
#pragma unroll
            for (int off = 32; off > 0; off >>= 1) {
                a0 += __shfl_xor(a0, off);
                a1 += __shfl_xor(a1, off);
                a2 += __shfl_xor(a2, off);
                a3 += __shfl_xor(a3, off);
            }
            if (lane == 0) {
                float* dw = dot_s[t & 1];
                dw[di + 0] = a0; dw[di + 1] = a1; dw[di + 2] = a2; dw[di + 3] = a3;
                LDS_ADD_REL(&mv_cnt);   // also signals: done reading Hs[(t-1)&1]
            }
            if (tid < 8) {   // wave 0 only: gates + publish
                while (LDS_LOAD_ACQ(&mv_cnt) < 4 * t) __builtin_amdgcn_s_sleep(0);
                const float* dr = dot_s[t & 1];
                float z = 1.0f / (1.0f + expf(-(xz_cur + dr[tid])));
                float g = tanhf(xh_cur + dr[8 + tid]);
                p_cur = (1.0f - z) * p_cur + z * g;   // P_{t+1}
                unsigned long long pr = ((unsigned long long)(unsigned)(t + 1) << 32)
                                      | (unsigned long long)__float_as_uint(p_cur);
                __hip_atomic_store(&Hbuf[(size_t)((t + 1) & 3) * NHH + base8 + tid], pr,
                                   __ATOMIC_RELAXED, __HIP_MEMORY_SCOPE_AGENT);
                // prefetch x-proj row t (used at iteration t+1)
                xz_cur = XZ[(size_t)t * NHH + base8 + tid];
                xh_cur = XH[(size_t)t * NHH + base8 + tid];
            }
        }
    } else {
        // ----------------- COMM role (waves 4-7) -----------------
        const int ct = tid - 256;   // 0..255
        for (int t = 1; t < TT; ++t) {
            // issue epoch-t loads BEFORE the local spin (hide one RTT)
            const unsigned long long* __restrict__ src = Hbuf + (size_t)(t & 3) * NHH;
            unsigned long long pv[8];
#pragma unroll
            for (int k = 0; k < 8; ++k)
                pv[k] = __hip_atomic_load(&src[k * 256 + ct], __ATOMIC_RELAXED, __HIP_MEMORY_SCOPE_AGENT);
            // Hs[t&1] currently holds P_{t-2}, read by matvec step t-1
            if (t > 1)
                while (LDS_LOAD_ACQ(&mv_cnt) < 4 * (t - 1)) __builtin_amdgcn_s_sleep(0);
            // validate tags == t (batched parallel retry)
            for (;;) {
                unsigned stale = 0;
#pragma unroll
                for (int k = 0; k < 8; ++k)
                    if ((unsigned)(pv[k] >> 32) != (unsigned)t) stale |= (1u << k);
                if (!stale) break;
                __builtin_amdgcn_s_sleep(1);
#pragma unroll
                for (int k = 0; k < 8; ++k)
                    if (stale & (1u << k))
                        pv[k] = __hip_atomic_load(&src[k * 256 + ct], __ATOMIC_RELAXED, __HIP_MEMORY_SCOPE_AGENT);
            }
            float* __restrict__ HB = Hs[t & 1];
#pragma unroll
            for (int k = 0; k < 8; ++k)
                HB[k * 256 + ct] = __uint_as_float((unsigned)pv[k]);
            if (lane == 0) LDS_ADD_REL(&fill_cnt);
        }
    }
}

// ---------------------------------------------------------------------------
// logits[r] = Wout[r,:] . P_1024   (epoch 1024 -> slot 0, value in low bits)
// ---------------------------------------------------------------------------
__global__ __launch_bounds__(256) void k_logits(const unsigned long long* __restrict__ Hbuf,
                                                const float* __restrict__ Wout,
                                                float* __restrict__ lg) {
    __shared__ float Hs[NHH];
    const int tid = threadIdx.x;
    for (int k = tid; k < NHH; k += 256) Hs[k] = __uint_as_float((unsigned)Hbuf[k]);
    __syncthreads();
    const int wave = tid >> 6, lane = tid & 63;
    const int row = blockIdx.x * 4 + wave;
    float a = 0.f;
#pragma unroll
    for (int c = 0; c < 8; ++c) {
        float4 w = *(const float4*)&Wout[(size_t)row * NHH + c * 256 + lane * 4];
        float4 h = *(const float4*)&Hs[c * 256 + lane * 4];
        a = fmaf(w.x, h.x, fmaf(w.y, h.y, fmaf(w.z, h.z, fmaf(w.w, h.w, a))));
    }
#pragma unroll
    for (int off = 32; off > 0; off >>= 1) a += __shfl_xor(a, off);
    if (lane == 0) lg[row] = a;
}

// ---------------------------------------------------------------------------
// softmax over 1000 logits, single block
// ---------------------------------------------------------------------------
__global__ __launch_bounds__(1024) void k_softmax(const float* __restrict__ lg,
                                                  float* __restrict__ out) {
    const int i = threadIdx.x;
    __shared__ float red[16];
    __shared__ float bc[2];
    float v = (i < CC) ? lg[i] : -3.0e38f;
    float m = v;
#pragma unroll
    for (int off = 32; off > 0; off >>= 1) m = fmaxf(m, __shfl_xor(m, off));
    if ((i & 63) == 0) red[i >> 6] = m;
    __syncthreads();
    if (i == 0) { float mm = red[0]; for (int k = 1; k < 16; ++k) mm = fmaxf(mm, red[k]); bc[0] = mm; }
    __syncthreads();
    float e = (i < CC) ? expf(v - bc[0]) : 0.f;
    float s = e;
#pragma unroll
    for (int off = 32; off > 0; off >>= 1) s += __shfl_xor(s, off);
    if ((i & 63) == 0) red[i >> 6] = s;
    __syncthreads();
    if (i == 0) { float ss = 0.f; for (int k = 0; k < 16; ++k) ss += red[k]; bc[1] = ss; }
    __syncthreads();
    if (i < CC) out[i] = e / bc[1];
}

extern "C" void kernel_launch(void* const* d_in, const int* in_sizes, int n_in,
                              void* d_out, int out_size, void* d_ws, size_t ws_size,
                              hipStream_t stream) {
    const float* x    = (const float*)d_in[0];
    const float* Wh   = (const float*)d_in[1];
    const float* Wz   = (const float*)d_in[2];
    // d_in[3] = Wr  (dead code in reference)
    const float* Uh   = (const float*)d_in[4];
    const float* Uz   = (const float*)d_in[5];
    const float* bz   = (const float*)d_in[6];
    // d_in[7] = Ur, d_in[8] = br (dead code)
    const float* Wout = (const float*)d_in[9];
    // d_in[10] = h0 (overwritten before first use since T>=1)
    const float* zt0  = (const float*)d_in[11];
    const float* ht0  = (const float*)d_in[12];
    const float* hp0  = (const float*)d_in[13];
    float* out = (float*)d_out;

    float* XH = (float*)d_ws;                                   // T*NH f32
    float* XZ = XH + (size_t)TT * NHH;                          // T*NH f32
    unsigned long long* Hbuf = (unsigned long long*)(XZ + (size_t)TT * NHH); // 4*NH u64
    float* lg = (float*)(Hbuf + 4 * NHH);                       // CC f32

    k_init<<<dim3((4 * NHH + 255) / 256), dim3(256), 0, stream>>>(Hbuf);
    k_gemm<<<dim3(NHH / 64, TT / 64, 2), dim3(256), 0, stream>>>(x, Wh, Wz, bz, XH, XZ);
    k_recur<<<dim3(256), dim3(512), 0, stream>>>(XH, XZ, Uh, Uz, zt0, ht0, hp0, Hbuf);
    k_logits<<<dim3(250), dim3(256), 0, stream>>>(Hbuf, Wout, lg);
    k_softmax<<<dim3(1), dim3(1024), 0, stream>>>(lg, out);
}